// Round 1
// baseline (341.669 us; speedup 1.0000x reference)
//
#include <hip/hip_runtime.h>

// DeformableConv1d: B=32, C=64, L=16384, COUT=64, K=1 (both convs are 1x1).
// out[b,co,l] = sum_ci Wr[co,ci] * lerp(x[b,ci,:], clamp(l + off[b,ci,l])) + br[co]
// off[b,c,l]  = sum_ci Wo[c,ci] * x[b,ci,l] + bo[c]

#define BDIM 256
#define BB   32
#define CC   64
#define LL   16384
#define CO   64
#define TL   64      // l-tile per block
#define PAD  68      // LDS row stride (floats): 68*4=272 B, 16B-aligned rows

__global__ __launch_bounds__(BDIM)
void deform_conv1d_kernel(const float* __restrict__ x,
                          const float* __restrict__ offw,
                          const float* __restrict__ offb,
                          const float* __restrict__ regw,
                          const float* __restrict__ regb,
                          float* __restrict__ out) {
    __shared__ float Xbuf[CC * PAD];    // x tile, then reused for deformed tile
    __shared__ float WtOff[CC * PAD];   // offset weights, transposed: [ci][co]
    __shared__ float WtReg[CC * PAD];   // regular weights, transposed: [ci][co]

    const int tid = threadIdx.x;
    const int lg0 = blockIdx.x * TL;    // global l base of this tile
    const int b   = blockIdx.y;

    // ---- stage x tile [64 ch][64 l] into LDS (coalesced float4) ----
    {
        const float* xb = x + (size_t)b * CC * LL + lg0;
        for (int i = tid; i < CC * (TL / 4); i += BDIM) {
            int ci = i >> 4;            // TL/4 = 16 float4 per row
            int f  = i & 15;
            float4 v = *(const float4*)(xb + (size_t)ci * LL + f * 4);
            *(float4*)(&Xbuf[ci * PAD + f * 4]) = v;
        }
    }
    // ---- stage weights transposed: Wt[ci][co] = W[co][ci] ----
    for (int i = tid; i < CC * CC; i += BDIM) {
        int co = i >> 6, ci = i & 63;
        WtOff[ci * PAD + co] = offw[i];
        WtReg[ci * PAD + co] = regw[i];
    }
    __syncthreads();

    // thread owns 4 channels x 4 l positions
    const int l0 = (tid & 15) * 4;       // local l base
    const int c0 = (tid >> 4) * 4;       // channel base

    // ---- matmul 1: per-channel offsets for this 4x4 tile ----
    float4 acc[4];
    {
        float4 bo = *(const float4*)(offb + c0);
        acc[0] = make_float4(bo.x, bo.x, bo.x, bo.x);
        acc[1] = make_float4(bo.y, bo.y, bo.y, bo.y);
        acc[2] = make_float4(bo.z, bo.z, bo.z, bo.z);
        acc[3] = make_float4(bo.w, bo.w, bo.w, bo.w);
    }
    #pragma unroll
    for (int ci = 0; ci < CC; ++ci) {
        float4 xv = *(const float4*)(&Xbuf[ci * PAD + l0]);   // x[ci][l0..l0+3]
        float4 wv = *(const float4*)(&WtOff[ci * PAD + c0]);  // Wo[c0..c0+3][ci]
        acc[0].x += wv.x * xv.x; acc[0].y += wv.x * xv.y; acc[0].z += wv.x * xv.z; acc[0].w += wv.x * xv.w;
        acc[1].x += wv.y * xv.x; acc[1].y += wv.y * xv.y; acc[1].z += wv.y * xv.z; acc[1].w += wv.y * xv.w;
        acc[2].x += wv.z * xv.x; acc[2].y += wv.z * xv.y; acc[2].z += wv.z * xv.z; acc[2].w += wv.z * xv.w;
        acc[3].x += wv.w * xv.x; acc[3].y += wv.w * xv.y; acc[3].z += wv.w * xv.z; acc[3].w += wv.w * xv.w;
    }

    // ---- gather + lerp: x_deform for this thread's 4x4 tile ----
    float xd[4][4];
    #pragma unroll
    for (int i2 = 0; i2 < 4; ++i2) {
        const float* xrow = x + (size_t)b * CC * LL + (size_t)(c0 + i2) * LL;
        float offv[4] = {acc[i2].x, acc[i2].y, acc[i2].z, acc[i2].w};
        #pragma unroll
        for (int j = 0; j < 4; ++j) {
            float pos = (float)(lg0 + l0 + j) + offv[j];
            pos = fminf(fmaxf(pos, 0.0f), (float)(LL - 1));
            float fl   = floorf(pos);
            float frac = pos - fl;
            int i0 = (int)fl;
            int i1 = i0 + (frac > 0.0f ? 1 : 0);   // == ceil(pos)
            float x0 = xrow[i0];
            float x1 = xrow[i1];
            xd[i2][j] = (1.0f - frac) * x0 + frac * x1;
        }
    }

    __syncthreads();   // everyone done reading Xbuf (matmul 1)
    #pragma unroll
    for (int i2 = 0; i2 < 4; ++i2)
        *(float4*)(&Xbuf[(c0 + i2) * PAD + l0]) =
            make_float4(xd[i2][0], xd[i2][1], xd[i2][2], xd[i2][3]);
    __syncthreads();

    // ---- matmul 2: regular conv on deformed tile ----
    float4 o[4];
    {
        float4 br = *(const float4*)(regb + c0);
        o[0] = make_float4(br.x, br.x, br.x, br.x);
        o[1] = make_float4(br.y, br.y, br.y, br.y);
        o[2] = make_float4(br.z, br.z, br.z, br.z);
        o[3] = make_float4(br.w, br.w, br.w, br.w);
    }
    #pragma unroll
    for (int ci = 0; ci < CC; ++ci) {
        float4 xv = *(const float4*)(&Xbuf[ci * PAD + l0]);
        float4 wv = *(const float4*)(&WtReg[ci * PAD + c0]);
        o[0].x += wv.x * xv.x; o[0].y += wv.x * xv.y; o[0].z += wv.x * xv.z; o[0].w += wv.x * xv.w;
        o[1].x += wv.y * xv.x; o[1].y += wv.y * xv.y; o[1].z += wv.y * xv.z; o[1].w += wv.y * xv.w;
        o[2].x += wv.z * xv.x; o[2].y += wv.z * xv.y; o[2].z += wv.z * xv.z; o[2].w += wv.z * xv.w;
        o[3].x += wv.w * xv.x; o[3].y += wv.w * xv.y; o[3].z += wv.w * xv.z; o[3].w += wv.w * xv.w;
    }

    // ---- coalesced float4 stores ----
    float* ob = out + (size_t)b * CO * LL + lg0;
    #pragma unroll
    for (int i2 = 0; i2 < 4; ++i2)
        *(float4*)(ob + (size_t)(c0 + i2) * LL + l0) = o[i2];
}

extern "C" void kernel_launch(void* const* d_in, const int* in_sizes, int n_in,
                              void* d_out, int out_size, void* d_ws, size_t ws_size,
                              hipStream_t stream) {
    const float* x    = (const float*)d_in[0];   // [32,64,16384]
    const float* offw = (const float*)d_in[1];   // [64,64,1]
    const float* offb = (const float*)d_in[2];   // [64]
    const float* regw = (const float*)d_in[3];   // [64,64,1]
    const float* regb = (const float*)d_in[4];   // [64]
    float* out = (float*)d_out;                  // [32,64,16384]

    dim3 grid(LL / TL, BB);
    dim3 block(BDIM);
    deform_conv1d_kernel<<<grid, block, 0, stream>>>(x, offw, offb, regw, regb, out);
}